// Round 6
// baseline (229.051 us; speedup 1.0000x reference)
//
#include <hip/hip_runtime.h>

#define CHANNELS 3
#define HW 512
#define KS 15
#define GPAD 7
#define TILE_W 64
#define TILE_H 32
#define HT (TILE_H + 2 * GPAD)   // 46 staged input rows (tile + vertical halo)
#define IN_STR 81                // odd stride: hot LDS read phases <=2-way aliasing (free)
#define WCOLS 20                 // 20 float4 = 80 staged cols [gx0-8, gx0+72)
#define NSTAGE (HT * WCOLS)      // 920 float4 stage items
#define NH (HT * 4)              // 184 h-pass items (row, 16-col chunk)
#define WIN (16 + KS - 1)        // 30-tap window per 16-output chunk
#define NZB 6                    // bc-planes per block: 96/6 = 16 z-blocks -> 2048 blocks = 8/CU

// LDS = 46*81*4 = 14904 B -> 8 blocks/CU (32 waves). VGPR cap 64 via (256,8).
// Cross-plane register double-buffer: loads for plane t+1 issued right after
// plane t's drain -> HBM busy during H/V compute (r4's loads were phase-locked).
__global__ __launch_bounds__(256, 8)
void gauss_blur_kernel(const float* __restrict__ x,
                       const float* __restrict__ sigma,
                       float* __restrict__ out, const int BC) {
    // Single LDS buffer, reused in place per plane:
    //   stage: input rows [gy0, gy0+46) x cols [gx0-8, gx0+72)  (46 x 80)
    //   mid  : horizontal result overwrites cols [0, 64)        (46 x 64)
    __shared__ float in_s[HT * IN_STR];

    const int tid   = threadIdx.x;   // 0..255
    const int tileX = blockIdx.x;    // 0..7
    const int tileY = blockIdx.y;    // 0..15
    const int z0    = blockIdx.z * NZB;

    const size_t plane = (size_t)HW * HW;
    const int gx0 = tileX * TILE_W;         // first output col of tile
    const int gy0 = tileY * TILE_H - GPAD;  // first staged row (global)
    const int ax0 = gx0 - 8;                // 16B-aligned staged-window start col
    const bool interior = (tileX >= 1) && (tileX <= (HW / TILE_W) - 2) &&
                          (tileY >= 1) && (tileY <= (HW / TILE_H) - 2);

    // ---- z-invariant stage geometry, hoisted out of the plane loop ----
    int  ldsoff[4], goff[4], grow[4], gcol[4];
    bool ok[4];
    #pragma unroll
    for (int s = 0; s < 4; ++s) {
        const int i = tid + 256 * s;
        ok[s] = (i < NSTAGE);
        const int r = i / WCOLS;
        const int q = i - r * WCOLS;
        ldsoff[s] = r * IN_STR + 4 * q;
        grow[s] = gy0 + r;
        gcol[s] = ax0 + 4 * q;
        goff[s] = grow[s] * HW + gcol[s];   // interior-path offset (always valid there)
    }
    // z-invariant V-pass mapping
    const int vc   = tid & (TILE_W - 1);
    const int vr0  = (tid >> 6) * 8;
    const int voff = (tileY * TILE_H + vr0) * HW + gx0 + vc;

    float4 v[4];
    auto issue_loads = [&](const float* xp) {
        if (interior) {
            #pragma unroll
            for (int s = 0; s < 4; ++s)
                if (ok[s]) v[s] = *(const float4*)(xp + goff[s]);
        } else {
            #pragma unroll
            for (int s = 0; s < 4; ++s) {
                v[s] = make_float4(0.f, 0.f, 0.f, 0.f);
                if (ok[s] && (unsigned)grow[s] < (unsigned)HW) {
                    const float* rowp = xp + (size_t)grow[s] * HW;
                    const int gc = gcol[s];
                    if (gc >= 0 && gc + 4 <= HW) {
                        v[s] = *(const float4*)(rowp + gc);
                    } else {
                        if ((unsigned)(gc + 0) < (unsigned)HW) v[s].x = rowp[gc + 0];
                        if ((unsigned)(gc + 1) < (unsigned)HW) v[s].y = rowp[gc + 1];
                        if ((unsigned)(gc + 2) < (unsigned)HW) v[s].z = rowp[gc + 2];
                        if ((unsigned)(gc + 3) < (unsigned)HW) v[s].w = rowp[gc + 3];
                    }
                }
            }
        }
    };

    // ---- prologue: issue plane z0's staging burst ----
    issue_loads(x + (size_t)z0 * plane);

    for (int t = 0; t < NZB; ++t) {
        const int bc = z0 + t;
        if (bc >= BC) break;   // block-uniform guard (BC=96 here: never taken)

        // weights for this plane: overlap the in-flight loads (independent of v[]);
        // wave-uniform -> pin to SGPRs via readfirstlane.
        float w[KS];
        {
            const float s = sigma[bc / CHANNELS];
            const float inv_denom = 1.0f / (2.0f * s * s + 1e-8f);
            float g[KS];
            float sum = 0.0f;
            #pragma unroll
            for (int i = 0; i < KS; ++i) {
                const float d = (float)(i - GPAD);
                g[i] = __expf(-d * d * inv_denom);
                sum += g[i];
            }
            const float inv = 1.0f / sum;
            #pragma unroll
            for (int i = 0; i < KS; ++i)
                w[i] = __int_as_float(__builtin_amdgcn_readfirstlane(__float_as_int(g[i] * inv)));
        }

        __syncthreads();   // previous plane's V-pass LDS reads done before drain

        // ---- drain plane t's loads into LDS ----
        #pragma unroll
        for (int s = 0; s < 4; ++s) {
            if (ok[s]) {
                float* d = &in_s[ldsoff[s]];
                d[0] = v[s].x; d[1] = v[s].y; d[2] = v[s].z; d[3] = v[s].w;
            }
        }
        // ---- issue plane t+1's staging burst (v[] dead after drain) ----
        if (t + 1 < NZB && bc + 1 < BC)
            issue_loads(x + (size_t)(bc + 1) * plane);
        __syncthreads();

        // ---- H-pass: LDS -> registers, accumulate on load. Item tid ->
        // (row tid>>2, 16-col chunk tid&3); 184 items. Output local col
        // oc = 16ch+o reads staged cols [oc+1, oc+30). Baseline tap order. ----
        float acc[16];
        #pragma unroll
        for (int o = 0; o < 16; ++o) acc[o] = 0.0f;
        const bool hwork = (tid < NH);
        if (hwork) {
            const int r  = tid >> 2;
            const int ch = tid & 3;
            const float* src = &in_s[r * IN_STR + 16 * ch + 1];
            #pragma unroll
            for (int j = 0; j < WIN; ++j) {
                const float vv = src[j];
                const int lo = (j - (KS - 1)) > 0 ? (j - (KS - 1)) : 0;
                const int hi = (j < 15) ? j : 15;
                #pragma unroll
                for (int o = lo; o <= hi; ++o)
                    acc[o] = fmaf(w[j - o], vv, acc[o]);
            }
        }
        __syncthreads();   // all stage reads done before in-place overwrite

        // ---- mid write-back into the same LDS buffer (cols 0..63) ----
        if (hwork) {
            const int r  = tid >> 2;
            const int ch = tid & 3;
            float* dst = &in_s[r * IN_STR + 16 * ch];
            #pragma unroll
            for (int o = 0; o < 16; ++o) dst[o] = acc[o];
        }
        __syncthreads();

        // ---- V-pass from LDS, accumulate on load; coalesced 256B/wave stores ----
        {
            float vacc[8];
            #pragma unroll
            for (int o = 0; o < 8; ++o) vacc[o] = 0.0f;
            #pragma unroll
            for (int j = 0; j < 8 + KS - 1; ++j) {     // 22 taps for 8 outputs
                const float vv = in_s[(vr0 + j) * IN_STR + vc];
                const int lo = (j - (KS - 1)) > 0 ? (j - (KS - 1)) : 0;
                const int hi = (j < 8) ? j : 7;
                #pragma unroll
                for (int o = lo; o <= hi; ++o)
                    vacc[o] = fmaf(w[j - o], vv, vacc[o]);
            }
            float* colp = out + (size_t)bc * plane + voff;
            #pragma unroll
            for (int o = 0; o < 8; ++o)
                colp[(size_t)o * HW] = vacc[o];
        }
    }
}

extern "C" void kernel_launch(void* const* d_in, const int* in_sizes, int n_in,
                              void* d_out, int out_size, void* d_ws, size_t ws_size,
                              hipStream_t stream) {
    const float* x     = (const float*)d_in[0];
    const float* sigma = (const float*)d_in[1];
    float* out         = (float*)d_out;
    const int B  = in_sizes[1];  // 32
    const int BC = B * CHANNELS; // 96
    dim3 grid(HW / TILE_W, HW / TILE_H, (BC + NZB - 1) / NZB);
    gauss_blur_kernel<<<grid, dim3(256, 1, 1), 0, stream>>>(x, sigma, out, BC);
}